// Round 21
// baseline (519.294 us; speedup 1.0000x reference)
//
#include <hip/hip_runtime.h>

#define KT 4
#define KN 20000        // NA == ND == 20000
#define KE 100000
#define KH 128
#define KL 2
#define KNT 40000       // NA + ND

typedef __attribute__((ext_vector_type(8))) short short8v;
typedef __attribute__((ext_vector_type(4))) float f32x4;

__device__ __forceinline__ short bf16rn(float x) {
    unsigned u = __float_as_uint(x);
    u = (u + 0x7fffu + ((u >> 16) & 1u)) >> 16;
    return (short)u;
}
__device__ __forceinline__ float bf16tof(short h) {
    return __uint_as_float(((unsigned)(unsigned short)h) << 16);
}
__device__ __forceinline__ short8v mk8(uint2 a, uint2 b) {
    union { unsigned u[4]; short8v s; } c;
    c.u[0] = a.x; c.u[1] = a.y; c.u[2] = b.x; c.u[3] = b.y;
    return c.s;
}
__device__ __forceinline__ float4 unp4(uint2 g) {
    float4 r;
    r.x = __uint_as_float(g.x << 16);
    r.y = __uint_as_float(g.x & 0xffff0000u);
    r.z = __uint_as_float(g.y << 16);
    r.w = __uint_as_float(g.y & 0xffff0000u);
    return r;
}

// ---------------------------------------------------------------------------
// CSR build: counts -> scan -> fill (packed (edge, src) pairs).  All 8 z.
// ---------------------------------------------------------------------------
__global__ void count_k(const int* __restrict__ ei_ad, const int* __restrict__ ei_da,
                        int* __restrict__ cnt) {
    int e = blockIdx.x * 256 + threadIdx.x;
    int z = blockIdx.y;                 // z = t*2 + et
    if (e >= KE) return;
    int t = z >> 1, et = z & 1;
    const int* ei = et ? ei_da : ei_ad;
    int dst = ei[(t * 2 + 1) * KE + e];
    atomicAdd(&cnt[z * KN + dst], 1);
}

__global__ void scan_k(int* __restrict__ cnt, int* __restrict__ offs) {
    __shared__ int s[256];
    int z = blockIdx.x, tid = threadIdx.x;
    const int CH = (KN + 255) / 256;    // 79
    int n0 = tid * CH;
    int lim = n0 < KN ? min(CH, KN - n0) : 0;
    long base = (long)z * KN + n0;
    int sum = 0;
    for (int i = 0; i < lim; ++i) sum += cnt[base + i];
    s[tid] = sum;
    __syncthreads();
    for (int off = 1; off < 256; off <<= 1) {
        int v = (tid >= off) ? s[tid - off] : 0;
        __syncthreads();
        s[tid] += v;
        __syncthreads();
    }
    int run = s[tid] - sum;             // exclusive prefix
    for (int i = 0; i < lim; ++i) {
        int c = cnt[base + i];
        offs[(long)z * (KN + 1) + n0 + i] = run;
        cnt[base + i] = run;            // becomes fill cursor
        run += c;
    }
    if (tid == 0) offs[(long)z * (KN + 1) + KN] = KE;
}

__global__ void fill_k(const int* __restrict__ ei_ad, const int* __restrict__ ei_da,
                       int* __restrict__ cur, int2* __restrict__ pes) {
    int e = blockIdx.x * 256 + threadIdx.x;
    int z = blockIdx.y;
    if (e >= KE) return;
    int t = z >> 1, et = z & 1;
    const int* ei = et ? ei_da : ei_ad;
    int src = ei[(t * 2 + 0) * KE + e];
    int dst = ei[(t * 2 + 1) * KE + e];
    int pos = atomicAdd(&cur[z * KN + dst], 1);
    pes[(long)z * KE + pos] = make_int2(e, src);
}

// ---------------------------------------------------------------------------
// W pre-split: wsp[((mat*2+h)*4 + kc)*4096 + col*32 + kk], k = kc*32+kk.
// mat = arr*8 + (t*2+l), arr: 0=w1_ad 1=w1_da 2=w2_ad 3=w2_da.
// ---------------------------------------------------------------------------
__global__ __launch_bounds__(256)
void wsplit_k(const float* __restrict__ w1_ad, const float* __restrict__ w1_da,
              const float* __restrict__ w2_ad, const float* __restrict__ w2_da,
              short* __restrict__ wsp) {
    int mat = blockIdx.x >> 3, part = blockIdx.x & 7;   // mat 0..31
    int arr = mat >> 3, rem = mat & 7;   // rem = t*2+l
    const float* src = (arr == 0 ? w1_ad : arr == 1 ? w1_da : arr == 2 ? w2_ad : w2_da)
                       + (long)rem * KH * KH;
    #pragma unroll
    for (int p = 0; p < 8; ++p) {
        int idx = part * 2048 + p * 256 + threadIdx.x;  // 16384 elems total
        int k = idx >> 7, c = idx & 127;
        float v = src[idx];
        short hi = bf16rn(v);
        short lo = bf16rn(v - bf16tof(hi));
        int chunk = k >> 5, kk = k & 31;
        long ohi = ((long)(mat * 2 + 0) * 4 + chunk) * 4096 + c * 32 + kk;
        long olo = ((long)(mat * 2 + 1) * 4 + chunk) * 4096 + c * 32 + kk;
        wsp[ohi] = hi;
        wsp[olo] = lo;
    }
}

// ---------------------------------------------------------------------------
// Fully fused per-layer kernel, 16-NODE TILES (10000 blocks, ~39/CU queue).
//   phase 0: gather 16 nodes -> bf16 T in LDS (2 passes)
//   phase 1: mid = relu(T @ W1 + b1) -> T in-place
//   phase 2: out = [relu](T @ W2 + b2) -> lay_out
// 4 waves: each owns 16 rows x 32 cols (acc[1][2]).
// ALIASING + DTYPE: l=0 fp32 inputs -> bf16 x1 ; l=1 bf16 x1 -> fp32 d_out.
// ---------------------------------------------------------------------------
__global__ __launch_bounds__(256)
void fused_k(const float* __restrict__ xa, const float* __restrict__ xd,
             const unsigned short* __restrict__ x1b,
             const float* __restrict__ ea_ad, const float* __restrict__ ea_da,
             const float* __restrict__ eps_ad, const float* __restrict__ eps_da,
             const int* __restrict__ offs, const int2* __restrict__ pes,
             const short* __restrict__ wsp,
             const float* __restrict__ b1_ad, const float* __restrict__ b1_da,
             const float* __restrict__ b2_ad, const float* __restrict__ b2_da,
             unsigned short* __restrict__ x1o, float* __restrict__ dout,
             int l) {
    __shared__ short T[16][132];        // 4.2 KB, agg then mid (in-place)

    int z = blockIdx.y, t = z >> 1, et = z & 1;
    int tid = threadIdx.x;
    int r0 = blockIdx.x * 16;

    // ---- phase 0: gather this block's 16 nodes into T ----
    {
        const float* ea  = (et ? ea_da : ea_ad) + (long)t * KE * KH;
        const float* eps = et ? eps_da : eps_ad;
        float scale = 1.0f + eps[t * KL + l];
        const int2* pz = pes + (long)z * KE;
        int li = tid & 31, grp = tid >> 5;

        if (l == 0) {
            const float* src = et ? (xd + (long)t * KN * KH) : (xa + (long)t * KN * KH);
            const float* dst = et ? (xa + (long)t * KN * KH) : (xd + (long)t * KN * KH);
            #pragma unroll
            for (int p = 0; p < 2; ++p) {
                int lr = p * 8 + grp;
                int node = r0 + lr;
                float4 r = make_float4(0.f, 0.f, 0.f, 0.f);
                if (node < KN) {
                    float4 dv = *(const float4*)(dst + (long)node * KH + li * 4);
                    float4 acc = make_float4(0.f, 0.f, 0.f, 0.f);
                    int beg = offs[(long)z * (KN + 1) + node];
                    int end = offs[(long)z * (KN + 1) + node + 1];
                    if (beg < end) {
                        int last = end - 1;
                        for (int i = beg; i < end; i += 4) {
                            int i0 = min(i, last), i1 = min(i + 1, last),
                                i2 = min(i + 2, last), i3 = min(i + 3, last);
                            int2 p0 = pz[i0], p1 = pz[i1], p2 = pz[i2], p3 = pz[i3];
                            float4 e0 = *(const float4*)(ea + (long)p0.x * KH + li * 4);
                            float4 e1 = *(const float4*)(ea + (long)p1.x * KH + li * 4);
                            float4 e2 = *(const float4*)(ea + (long)p2.x * KH + li * 4);
                            float4 e3 = *(const float4*)(ea + (long)p3.x * KH + li * 4);
                            float4 x0 = *(const float4*)(src + (long)p0.y * KH + li * 4);
                            float4 x1v = *(const float4*)(src + (long)p1.y * KH + li * 4);
                            float4 x2 = *(const float4*)(src + (long)p2.y * KH + li * 4);
                            float4 x3 = *(const float4*)(src + (long)p3.y * KH + li * 4);
                            float4 es4[4] = {e0, e1, e2, e3};
                            float4 xs[4] = {x0, x1v, x2, x3};
                            #pragma unroll
                            for (int u = 0; u < 4; ++u) {
                                float m = (i + u <= last) ? 1.0f : 0.0f;
                                acc.x = fmaf(m, fmaxf(xs[u].x + es4[u].x, 0.f), acc.x);
                                acc.y = fmaf(m, fmaxf(xs[u].y + es4[u].y, 0.f), acc.y);
                                acc.z = fmaf(m, fmaxf(xs[u].z + es4[u].z, 0.f), acc.z);
                                acc.w = fmaf(m, fmaxf(xs[u].w + es4[u].w, 0.f), acc.w);
                            }
                        }
                    }
                    r.x = fmaf(scale, dv.x, acc.x);
                    r.y = fmaf(scale, dv.y, acc.y);
                    r.z = fmaf(scale, dv.z, acc.z);
                    r.w = fmaf(scale, dv.w, acc.w);
                }
                unsigned short h0 = (unsigned short)bf16rn(r.x);
                unsigned short h1 = (unsigned short)bf16rn(r.y);
                unsigned short h2 = (unsigned short)bf16rn(r.z);
                unsigned short h3 = (unsigned short)bf16rn(r.w);
                *(uint2*)&T[lr][li * 4] = make_uint2(((unsigned)h1 << 16) | h0,
                                                     ((unsigned)h3 << 16) | h2);
            }
        } else {
            const unsigned short* base = x1b + (long)t * KNT * KH;
            const unsigned short* srcb = et ? (base + (long)KN * KH) : base;
            const unsigned short* dstb = et ? base : (base + (long)KN * KH);
            #pragma unroll
            for (int p = 0; p < 2; ++p) {
                int lr = p * 8 + grp;
                int node = r0 + lr;
                float4 r = make_float4(0.f, 0.f, 0.f, 0.f);
                if (node < KN) {
                    float4 dv = unp4(*(const uint2*)(dstb + (long)node * KH + li * 4));
                    float4 acc = make_float4(0.f, 0.f, 0.f, 0.f);
                    int beg = offs[(long)z * (KN + 1) + node];
                    int end = offs[(long)z * (KN + 1) + node + 1];
                    if (beg < end) {
                        int last = end - 1;
                        for (int i = beg; i < end; i += 4) {
                            int i0 = min(i, last), i1 = min(i + 1, last),
                                i2 = min(i + 2, last), i3 = min(i + 3, last);
                            int2 p0 = pz[i0], p1 = pz[i1], p2 = pz[i2], p3 = pz[i3];
                            float4 e0 = *(const float4*)(ea + (long)p0.x * KH + li * 4);
                            float4 e1 = *(const float4*)(ea + (long)p1.x * KH + li * 4);
                            float4 e2 = *(const float4*)(ea + (long)p2.x * KH + li * 4);
                            float4 e3 = *(const float4*)(ea + (long)p3.x * KH + li * 4);
                            uint2 g0 = *(const uint2*)(srcb + (long)p0.y * KH + li * 4);
                            uint2 g1 = *(const uint2*)(srcb + (long)p1.y * KH + li * 4);
                            uint2 g2 = *(const uint2*)(srcb + (long)p2.y * KH + li * 4);
                            uint2 g3 = *(const uint2*)(srcb + (long)p3.y * KH + li * 4);
                            float4 es4[4] = {e0, e1, e2, e3};
                            float4 xs[4] = {unp4(g0), unp4(g1), unp4(g2), unp4(g3)};
                            #pragma unroll
                            for (int u = 0; u < 4; ++u) {
                                float m = (i + u <= last) ? 1.0f : 0.0f;
                                acc.x = fmaf(m, fmaxf(xs[u].x + es4[u].x, 0.f), acc.x);
                                acc.y = fmaf(m, fmaxf(xs[u].y + es4[u].y, 0.f), acc.y);
                                acc.z = fmaf(m, fmaxf(xs[u].z + es4[u].z, 0.f), acc.z);
                                acc.w = fmaf(m, fmaxf(xs[u].w + es4[u].w, 0.f), acc.w);
                            }
                        }
                    }
                    r.x = fmaf(scale, dv.x, acc.x);
                    r.y = fmaf(scale, dv.y, acc.y);
                    r.z = fmaf(scale, dv.z, acc.z);
                    r.w = fmaf(scale, dv.w, acc.w);
                }
                unsigned short h0 = (unsigned short)bf16rn(r.x);
                unsigned short h1 = (unsigned short)bf16rn(r.y);
                unsigned short h2 = (unsigned short)bf16rn(r.z);
                unsigned short h3 = (unsigned short)bf16rn(r.w);
                *(uint2*)&T[lr][li * 4] = make_uint2(((unsigned)h1 << 16) | h0,
                                                     ((unsigned)h3 << 16) | h2);
            }
        }
    }
    __syncthreads();

    int mat1 = (0 * 2 + et) * 8 + t * 2 + l;
    int mat2 = (1 * 2 + et) * 8 + t * 2 + l;
    const float* Bp1 = (et ? b1_da : b1_ad) + (long)(t * KL + l) * KH;
    const float* Bp2 = (et ? b2_da : b2_ad) + (long)(t * KL + l) * KH;

    int lane = tid & 63, wid = tid >> 6;     // wave owns 16 rows x 32 cols
    int lrow = lane & 15, lq = lane >> 4;

    f32x4 acc[2];
    acc[0] = (f32x4){0.f, 0.f, 0.f, 0.f};
    acc[1] = (f32x4){0.f, 0.f, 0.f, 0.f};

    // ---- phase 1: acc = T(agg) @ W1 ----
    #pragma unroll
    for (int kc = 0; kc < 4; ++kc) {
        const short* whp = wsp + ((long)(mat1 * 2 + 0) * 4 + kc) * 4096;
        const short* wlp = wsp + ((long)(mat1 * 2 + 1) * 4 + kc) * 4096;
        int lr = lrow;
        int co = kc * 32 + lq * 8;
        short8v ahi = mk8(*(const uint2*)&T[lr][co],
                          *(const uint2*)&T[lr][co + 4]);
        #pragma unroll
        for (int j = 0; j < 2; ++j) {
            int off = (wid * 32 + j * 16 + lrow) * 32 + lq * 8;
            short8v bhi = *(const short8v*)(whp + off);
            short8v blo = *(const short8v*)(wlp + off);
            acc[j] = __builtin_amdgcn_mfma_f32_16x16x32_bf16(bhi, ahi, acc[j], 0, 0, 0);
            acc[j] = __builtin_amdgcn_mfma_f32_16x16x32_bf16(blo, ahi, acc[j], 0, 0, 0);
        }
    }

    __syncthreads();   // phase-1 reads complete before in-place overwrite

    // ---- epilogue 1: bias + relu -> bf16 -> T (in place) ----
    #pragma unroll
    for (int j = 0; j < 2; ++j) {
        int col = wid * 32 + j * 16 + lq * 4;
        float4 b4 = *(const float4*)&Bp1[col];
        f32x4 a = acc[j];
        float v0 = fmaxf(a[0] + b4.x, 0.f);
        float v1 = fmaxf(a[1] + b4.y, 0.f);
        float v2 = fmaxf(a[2] + b4.z, 0.f);
        float v3 = fmaxf(a[3] + b4.w, 0.f);
        unsigned short h0 = (unsigned short)bf16rn(v0);
        unsigned short h1 = (unsigned short)bf16rn(v1);
        unsigned short h2 = (unsigned short)bf16rn(v2);
        unsigned short h3 = (unsigned short)bf16rn(v3);
        *(uint2*)&T[lrow][col] = make_uint2(((unsigned)h1 << 16) | h0,
                                            ((unsigned)h3 << 16) | h2);
    }
    __syncthreads();

    // ---- phase 2: acc = T(mid) @ W2 ----
    acc[0] = (f32x4){0.f, 0.f, 0.f, 0.f};
    acc[1] = (f32x4){0.f, 0.f, 0.f, 0.f};

    #pragma unroll
    for (int kc = 0; kc < 4; ++kc) {
        const short* whp = wsp + ((long)(mat2 * 2 + 0) * 4 + kc) * 4096;
        const short* wlp = wsp + ((long)(mat2 * 2 + 1) * 4 + kc) * 4096;
        int lr = lrow;
        int co = kc * 32 + lq * 8;
        short8v ahi = mk8(*(const uint2*)&T[lr][co],
                          *(const uint2*)&T[lr][co + 4]);
        #pragma unroll
        for (int j = 0; j < 2; ++j) {
            int off = (wid * 32 + j * 16 + lrow) * 32 + lq * 8;
            short8v bhi = *(const short8v*)(whp + off);
            short8v blo = *(const short8v*)(wlp + off);
            acc[j] = __builtin_amdgcn_mfma_f32_16x16x32_bf16(bhi, ahi, acc[j], 0, 0, 0);
            acc[j] = __builtin_amdgcn_mfma_f32_16x16x32_bf16(blo, ahi, acc[j], 0, 0, 0);
        }
    }

    // ---- epilogue 2 ----
    {
        int node = r0 + lrow;
        if (node < KN) {
            #pragma unroll
            for (int j = 0; j < 2; ++j) {
                int col = wid * 32 + j * 16 + lq * 4;
                float4 b4 = *(const float4*)&Bp2[col];
                f32x4 a = acc[j];
                float4 v;
                v.x = a[0] + b4.x; v.y = a[1] + b4.y;
                v.z = a[2] + b4.z; v.w = a[3] + b4.w;
                long row_off = (long)t * KNT * KH + (et == 0 ? (long)KN * KH : 0)
                             + (long)node * KH + col;
                if (l == 0) {
                    v.x = fmaxf(v.x, 0.f); v.y = fmaxf(v.y, 0.f);
                    v.z = fmaxf(v.z, 0.f); v.w = fmaxf(v.w, 0.f);
                    unsigned short h0 = (unsigned short)bf16rn(v.x);
                    unsigned short h1 = (unsigned short)bf16rn(v.y);
                    unsigned short h2 = (unsigned short)bf16rn(v.z);
                    unsigned short h3 = (unsigned short)bf16rn(v.w);
                    *(uint2*)&x1o[row_off] = make_uint2(((unsigned)h1 << 16) | h0,
                                                        ((unsigned)h3 << 16) | h2);
                } else {
                    *(float4*)&dout[row_off] = v;
                }
            }
        }
    }
}

// ---------------------------------------------------------------------------
extern "C" void kernel_launch(void* const* d_in, const int* in_sizes, int n_in,
                              void* d_out_v, int out_size, void* d_ws, size_t ws_size,
                              hipStream_t stream) {
    const float* x_a    = (const float*)d_in[0];
    const float* x_d    = (const float*)d_in[1];
    const float* ea_ad  = (const float*)d_in[2];
    const float* ea_da  = (const float*)d_in[3];
    const int*   ei_ad  = (const int*)d_in[4];
    const int*   ei_da  = (const int*)d_in[5];
    const float* w1_ad  = (const float*)d_in[6];
    const float* b1_ad  = (const float*)d_in[7];
    const float* w2_ad  = (const float*)d_in[8];
    const float* b2_ad  = (const float*)d_in[9];
    const float* eps_ad = (const float*)d_in[10];
    const float* w1_da  = (const float*)d_in[11];
    const float* b1_da  = (const float*)d_in[12];
    const float* w2_da  = (const float*)d_in[13];
    const float* b2_da  = (const float*)d_in[14];
    const float* eps_da = (const float*)d_in[15];
    float* out = (float*)d_out_v;

    // workspace layout: x1 bf16 ping | offs | cur | pes | wsp  (~47 MB)
    unsigned short* x1 = (unsigned short*)d_ws;          // KT*KNT*KH bf16
    int*   offs = (int*)(x1 + (size_t)KT * KNT * KH);
    int*   cur  = offs + (size_t)8 * (KN + 1);
    int2*  pes  = (int2*)(cur + (size_t)8 * KN);
    short* wsp  = (short*)(pes + (size_t)8 * KE);        // 1,048,576 shorts

    hipMemsetAsync(cur, 0, (size_t)8 * KN * sizeof(int), stream);
    wsplit_k<<<256, 256, 0, stream>>>(w1_ad, w1_da, w2_ad, w2_da, wsp);

    dim3 eg((KE + 255) / 256, 8);
    count_k<<<eg, 256, 0, stream>>>(ei_ad, ei_da, cur);
    scan_k<<<8, 256, 0, stream>>>(cur, offs);
    fill_k<<<eg, 256, 0, stream>>>(ei_ad, ei_da, cur, pes);

    dim3 gg((KN + 15) / 16, 8);          // 1250 x 8 = 10000 blocks
    // l=0: fp32 inputs -> bf16 x1 ;  l=1: bf16 x1 -> fp32 d_out
    fused_k<<<gg, 256, 0, stream>>>(x_a, x_d, (const unsigned short*)x1,
                                    ea_ad, ea_da, eps_ad, eps_da,
                                    offs, pes, wsp,
                                    b1_ad, b1_da, b2_ad, b2_da,
                                    x1, out, 0);
    fused_k<<<gg, 256, 0, stream>>>(x_a, x_d, (const unsigned short*)x1,
                                    ea_ad, ea_da, eps_ad, eps_da,
                                    offs, pes, wsp,
                                    b1_ad, b1_da, b2_ad, b2_da,
                                    x1, out, 1);
}

// Round 22
// 479.357 us; speedup vs baseline: 1.0833x; 1.0833x over previous
//
#include <hip/hip_runtime.h>

#define KT 4
#define KN 20000        // NA == ND == 20000
#define KE 100000
#define KH 128
#define KL 2
#define KNT 40000       // NA + ND

typedef __attribute__((ext_vector_type(8))) short short8v;
typedef __attribute__((ext_vector_type(4))) float f32x4;

__device__ __forceinline__ short bf16rn(float x) {
    unsigned u = __float_as_uint(x);
    u = (u + 0x7fffu + ((u >> 16) & 1u)) >> 16;
    return (short)u;
}
__device__ __forceinline__ float bf16tof(short h) {
    return __uint_as_float(((unsigned)(unsigned short)h) << 16);
}
__device__ __forceinline__ short8v mk8(uint2 a, uint2 b) {
    union { unsigned u[4]; short8v s; } c;
    c.u[0] = a.x; c.u[1] = a.y; c.u[2] = b.x; c.u[3] = b.y;
    return c.s;
}
__device__ __forceinline__ float4 unp4(uint2 g) {
    float4 r;
    r.x = __uint_as_float(g.x << 16);
    r.y = __uint_as_float(g.x & 0xffff0000u);
    r.z = __uint_as_float(g.y << 16);
    r.w = __uint_as_float(g.y & 0xffff0000u);
    return r;
}

// ---------------------------------------------------------------------------
// CSR build: counts -> scan -> fill (packed (edge, src) pairs).  All 8 z.
// ---------------------------------------------------------------------------
__global__ void count_k(const int* __restrict__ ei_ad, const int* __restrict__ ei_da,
                        int* __restrict__ cnt) {
    int e = blockIdx.x * 256 + threadIdx.x;
    int z = blockIdx.y;                 // z = t*2 + et
    if (e >= KE) return;
    int t = z >> 1, et = z & 1;
    const int* ei = et ? ei_da : ei_ad;
    int dst = ei[(t * 2 + 1) * KE + e];
    atomicAdd(&cnt[z * KN + dst], 1);
}

__global__ void scan_k(int* __restrict__ cnt, int* __restrict__ offs) {
    __shared__ int s[256];
    int z = blockIdx.x, tid = threadIdx.x;
    const int CH = (KN + 255) / 256;    // 79
    int n0 = tid * CH;
    int lim = n0 < KN ? min(CH, KN - n0) : 0;
    long base = (long)z * KN + n0;
    int sum = 0;
    for (int i = 0; i < lim; ++i) sum += cnt[base + i];
    s[tid] = sum;
    __syncthreads();
    for (int off = 1; off < 256; off <<= 1) {
        int v = (tid >= off) ? s[tid - off] : 0;
        __syncthreads();
        s[tid] += v;
        __syncthreads();
    }
    int run = s[tid] - sum;             // exclusive prefix
    for (int i = 0; i < lim; ++i) {
        int c = cnt[base + i];
        offs[(long)z * (KN + 1) + n0 + i] = run;
        cnt[base + i] = run;            // becomes fill cursor
        run += c;
    }
    if (tid == 0) offs[(long)z * (KN + 1) + KN] = KE;
}

__global__ void fill_k(const int* __restrict__ ei_ad, const int* __restrict__ ei_da,
                       int* __restrict__ cur, int2* __restrict__ pes) {
    int e = blockIdx.x * 256 + threadIdx.x;
    int z = blockIdx.y;
    if (e >= KE) return;
    int t = z >> 1, et = z & 1;
    const int* ei = et ? ei_da : ei_ad;
    int src = ei[(t * 2 + 0) * KE + e];
    int dst = ei[(t * 2 + 1) * KE + e];
    int pos = atomicAdd(&cur[z * KN + dst], 1);
    pes[(long)z * KE + pos] = make_int2(e, src);
}

// ---------------------------------------------------------------------------
// W pre-split: wsp[((mat*2+h)*4 + kc)*4096 + col*32 + kk], k = kc*32+kk.
// mat = arr*8 + (t*2+l), arr: 0=w1_ad 1=w1_da 2=w2_ad 3=w2_da.
// ---------------------------------------------------------------------------
__global__ __launch_bounds__(256)
void wsplit_k(const float* __restrict__ w1_ad, const float* __restrict__ w1_da,
              const float* __restrict__ w2_ad, const float* __restrict__ w2_da,
              short* __restrict__ wsp) {
    int mat = blockIdx.x >> 3, part = blockIdx.x & 7;   // mat 0..31
    int arr = mat >> 3, rem = mat & 7;   // rem = t*2+l
    const float* src = (arr == 0 ? w1_ad : arr == 1 ? w1_da : arr == 2 ? w2_ad : w2_da)
                       + (long)rem * KH * KH;
    #pragma unroll
    for (int p = 0; p < 8; ++p) {
        int idx = part * 2048 + p * 256 + threadIdx.x;  // 16384 elems total
        int k = idx >> 7, c = idx & 127;
        float v = src[idx];
        short hi = bf16rn(v);
        short lo = bf16rn(v - bf16tof(hi));
        int chunk = k >> 5, kk = k & 31;
        long ohi = ((long)(mat * 2 + 0) * 4 + chunk) * 4096 + c * 32 + kk;
        long olo = ((long)(mat * 2 + 1) * 4 + chunk) * 4096 + c * 32 + kk;
        wsp[ohi] = hi;
        wsp[olo] = lo;
    }
}

// ---------------------------------------------------------------------------
// Fully fused per-layer kernel, 32-NODE TILES (5000 blocks), 8-DEEP gather
// batches: one load->wait->accumulate round for deg<=8 nodes (16 row
// requests in flight; clamped duplicates hit cache).  LDS 8.4 KB.
//   phase 0: gather 32 nodes -> bf16 T in LDS
//   phase 1: mid = relu(T @ W1 + b1) -> T in-place
//   phase 2: out = [relu](T @ W2 + b2) -> lay_out
// 4 waves: each owns 32 rows x 32 cols (acc[2][2]).
// ALIASING + DTYPE: l=0 fp32 inputs -> bf16 x1 ; l=1 bf16 x1 -> fp32 d_out.
// ---------------------------------------------------------------------------
__global__ __launch_bounds__(256)
void fused_k(const float* __restrict__ xa, const float* __restrict__ xd,
             const unsigned short* __restrict__ x1b,
             const float* __restrict__ ea_ad, const float* __restrict__ ea_da,
             const float* __restrict__ eps_ad, const float* __restrict__ eps_da,
             const int* __restrict__ offs, const int2* __restrict__ pes,
             const short* __restrict__ wsp,
             const float* __restrict__ b1_ad, const float* __restrict__ b1_da,
             const float* __restrict__ b2_ad, const float* __restrict__ b2_da,
             unsigned short* __restrict__ x1o, float* __restrict__ dout,
             int l) {
    __shared__ short T[32][132];        // 8.4 KB, agg then mid (in-place)

    int z = blockIdx.y, t = z >> 1, et = z & 1;
    int tid = threadIdx.x;
    int r0 = blockIdx.x * 32;

    // ---- phase 0: gather this block's 32 nodes into T ----
    {
        const float* ea  = (et ? ea_da : ea_ad) + (long)t * KE * KH;
        const float* eps = et ? eps_da : eps_ad;
        float scale = 1.0f + eps[t * KL + l];
        const int2* pz = pes + (long)z * KE;
        int li = tid & 31, grp = tid >> 5;

        if (l == 0) {
            const float* src = et ? (xd + (long)t * KN * KH) : (xa + (long)t * KN * KH);
            const float* dst = et ? (xa + (long)t * KN * KH) : (xd + (long)t * KN * KH);
            #pragma unroll
            for (int p = 0; p < 4; ++p) {
                int lr = p * 8 + grp;
                int node = r0 + lr;
                float4 r = make_float4(0.f, 0.f, 0.f, 0.f);
                if (node < KN) {
                    float4 dv = *(const float4*)(dst + (long)node * KH + li * 4);
                    float4 acc = make_float4(0.f, 0.f, 0.f, 0.f);
                    int beg = offs[(long)z * (KN + 1) + node];
                    int end = offs[(long)z * (KN + 1) + node + 1];
                    if (beg < end) {
                        int last = end - 1;
                        for (int i = beg; i < end; i += 8) {
                            int2 pp[8];
                            #pragma unroll
                            for (int u = 0; u < 8; ++u) pp[u] = pz[min(i + u, last)];
                            float4 ev[8];
                            #pragma unroll
                            for (int u = 0; u < 8; ++u)
                                ev[u] = *(const float4*)(ea + (long)pp[u].x * KH + li * 4);
                            float4 xv[8];
                            #pragma unroll
                            for (int u = 0; u < 8; ++u)
                                xv[u] = *(const float4*)(src + (long)pp[u].y * KH + li * 4);
                            #pragma unroll
                            for (int u = 0; u < 8; ++u) {
                                float m = (i + u <= last) ? 1.0f : 0.0f;
                                acc.x = fmaf(m, fmaxf(xv[u].x + ev[u].x, 0.f), acc.x);
                                acc.y = fmaf(m, fmaxf(xv[u].y + ev[u].y, 0.f), acc.y);
                                acc.z = fmaf(m, fmaxf(xv[u].z + ev[u].z, 0.f), acc.z);
                                acc.w = fmaf(m, fmaxf(xv[u].w + ev[u].w, 0.f), acc.w);
                            }
                        }
                    }
                    r.x = fmaf(scale, dv.x, acc.x);
                    r.y = fmaf(scale, dv.y, acc.y);
                    r.z = fmaf(scale, dv.z, acc.z);
                    r.w = fmaf(scale, dv.w, acc.w);
                }
                unsigned short h0 = (unsigned short)bf16rn(r.x);
                unsigned short h1 = (unsigned short)bf16rn(r.y);
                unsigned short h2 = (unsigned short)bf16rn(r.z);
                unsigned short h3 = (unsigned short)bf16rn(r.w);
                *(uint2*)&T[lr][li * 4] = make_uint2(((unsigned)h1 << 16) | h0,
                                                     ((unsigned)h3 << 16) | h2);
            }
        } else {
            const unsigned short* base = x1b + (long)t * KNT * KH;
            const unsigned short* srcb = et ? (base + (long)KN * KH) : base;
            const unsigned short* dstb = et ? base : (base + (long)KN * KH);
            #pragma unroll
            for (int p = 0; p < 4; ++p) {
                int lr = p * 8 + grp;
                int node = r0 + lr;
                float4 r = make_float4(0.f, 0.f, 0.f, 0.f);
                if (node < KN) {
                    float4 dv = unp4(*(const uint2*)(dstb + (long)node * KH + li * 4));
                    float4 acc = make_float4(0.f, 0.f, 0.f, 0.f);
                    int beg = offs[(long)z * (KN + 1) + node];
                    int end = offs[(long)z * (KN + 1) + node + 1];
                    if (beg < end) {
                        int last = end - 1;
                        for (int i = beg; i < end; i += 8) {
                            int2 pp[8];
                            #pragma unroll
                            for (int u = 0; u < 8; ++u) pp[u] = pz[min(i + u, last)];
                            float4 ev[8];
                            #pragma unroll
                            for (int u = 0; u < 8; ++u)
                                ev[u] = *(const float4*)(ea + (long)pp[u].x * KH + li * 4);
                            uint2 gv[8];
                            #pragma unroll
                            for (int u = 0; u < 8; ++u)
                                gv[u] = *(const uint2*)(srcb + (long)pp[u].y * KH + li * 4);
                            #pragma unroll
                            for (int u = 0; u < 8; ++u) {
                                float m = (i + u <= last) ? 1.0f : 0.0f;
                                float4 xv = unp4(gv[u]);
                                acc.x = fmaf(m, fmaxf(xv.x + ev[u].x, 0.f), acc.x);
                                acc.y = fmaf(m, fmaxf(xv.y + ev[u].y, 0.f), acc.y);
                                acc.z = fmaf(m, fmaxf(xv.z + ev[u].z, 0.f), acc.z);
                                acc.w = fmaf(m, fmaxf(xv.w + ev[u].w, 0.f), acc.w);
                            }
                        }
                    }
                    r.x = fmaf(scale, dv.x, acc.x);
                    r.y = fmaf(scale, dv.y, acc.y);
                    r.z = fmaf(scale, dv.z, acc.z);
                    r.w = fmaf(scale, dv.w, acc.w);
                }
                unsigned short h0 = (unsigned short)bf16rn(r.x);
                unsigned short h1 = (unsigned short)bf16rn(r.y);
                unsigned short h2 = (unsigned short)bf16rn(r.z);
                unsigned short h3 = (unsigned short)bf16rn(r.w);
                *(uint2*)&T[lr][li * 4] = make_uint2(((unsigned)h1 << 16) | h0,
                                                     ((unsigned)h3 << 16) | h2);
            }
        }
    }
    __syncthreads();

    int mat1 = (0 * 2 + et) * 8 + t * 2 + l;
    int mat2 = (1 * 2 + et) * 8 + t * 2 + l;
    const float* Bp1 = (et ? b1_da : b1_ad) + (long)(t * KL + l) * KH;
    const float* Bp2 = (et ? b2_da : b2_ad) + (long)(t * KL + l) * KH;

    int lane = tid & 63, wid = tid >> 6;     // wave owns 32 rows x 32 cols
    int lrow = lane & 15, lq = lane >> 4;

    f32x4 acc[2][2];
    #pragma unroll
    for (int i = 0; i < 2; ++i)
        #pragma unroll
        for (int j = 0; j < 2; ++j) acc[i][j] = (f32x4){0.f, 0.f, 0.f, 0.f};

    // ---- phase 1: acc = T(agg) @ W1 ----
    #pragma unroll
    for (int kc = 0; kc < 4; ++kc) {
        const short* whp = wsp + ((long)(mat1 * 2 + 0) * 4 + kc) * 4096;
        const short* wlp = wsp + ((long)(mat1 * 2 + 1) * 4 + kc) * 4096;
        short8v bhi[2], blo[2];
        #pragma unroll
        for (int j = 0; j < 2; ++j) {
            int off = (wid * 32 + j * 16 + lrow) * 32 + lq * 8;
            bhi[j] = *(const short8v*)(whp + off);
            blo[j] = *(const short8v*)(wlp + off);
        }
        #pragma unroll
        for (int i = 0; i < 2; ++i) {
            int lr = i * 16 + lrow;
            int co = kc * 32 + lq * 8;
            short8v ahi = mk8(*(const uint2*)&T[lr][co],
                              *(const uint2*)&T[lr][co + 4]);
            #pragma unroll
            for (int j = 0; j < 2; ++j) {
                acc[i][j] = __builtin_amdgcn_mfma_f32_16x16x32_bf16(bhi[j], ahi, acc[i][j], 0, 0, 0);
                acc[i][j] = __builtin_amdgcn_mfma_f32_16x16x32_bf16(blo[j], ahi, acc[i][j], 0, 0, 0);
            }
        }
    }

    __syncthreads();   // phase-1 reads complete before in-place overwrite

    // ---- epilogue 1: bias + relu -> bf16 -> T (in place) ----
    #pragma unroll
    for (int i = 0; i < 2; ++i) {
        int lr = i * 16 + lrow;
        #pragma unroll
        for (int j = 0; j < 2; ++j) {
            int col = wid * 32 + j * 16 + lq * 4;
            float4 b4 = *(const float4*)&Bp1[col];
            f32x4 a = acc[i][j];
            float v0 = fmaxf(a[0] + b4.x, 0.f);
            float v1 = fmaxf(a[1] + b4.y, 0.f);
            float v2 = fmaxf(a[2] + b4.z, 0.f);
            float v3 = fmaxf(a[3] + b4.w, 0.f);
            unsigned short h0 = (unsigned short)bf16rn(v0);
            unsigned short h1 = (unsigned short)bf16rn(v1);
            unsigned short h2 = (unsigned short)bf16rn(v2);
            unsigned short h3 = (unsigned short)bf16rn(v3);
            *(uint2*)&T[lr][col] = make_uint2(((unsigned)h1 << 16) | h0,
                                              ((unsigned)h3 << 16) | h2);
        }
    }
    __syncthreads();

    // ---- phase 2: acc = T(mid) @ W2 ----
    #pragma unroll
    for (int i = 0; i < 2; ++i)
        #pragma unroll
        for (int j = 0; j < 2; ++j) acc[i][j] = (f32x4){0.f, 0.f, 0.f, 0.f};

    #pragma unroll
    for (int kc = 0; kc < 4; ++kc) {
        const short* whp = wsp + ((long)(mat2 * 2 + 0) * 4 + kc) * 4096;
        const short* wlp = wsp + ((long)(mat2 * 2 + 1) * 4 + kc) * 4096;
        short8v bhi[2], blo[2];
        #pragma unroll
        for (int j = 0; j < 2; ++j) {
            int off = (wid * 32 + j * 16 + lrow) * 32 + lq * 8;
            bhi[j] = *(const short8v*)(whp + off);
            blo[j] = *(const short8v*)(wlp + off);
        }
        #pragma unroll
        for (int i = 0; i < 2; ++i) {
            int lr = i * 16 + lrow;
            int co = kc * 32 + lq * 8;
            short8v ahi = mk8(*(const uint2*)&T[lr][co],
                              *(const uint2*)&T[lr][co + 4]);
            #pragma unroll
            for (int j = 0; j < 2; ++j) {
                acc[i][j] = __builtin_amdgcn_mfma_f32_16x16x32_bf16(bhi[j], ahi, acc[i][j], 0, 0, 0);
                acc[i][j] = __builtin_amdgcn_mfma_f32_16x16x32_bf16(blo[j], ahi, acc[i][j], 0, 0, 0);
            }
        }
    }

    // ---- epilogue 2 ----
    #pragma unroll
    for (int i = 0; i < 2; ++i) {
        int node = r0 + i * 16 + lrow;
        if (node >= KN) continue;
        #pragma unroll
        for (int j = 0; j < 2; ++j) {
            int col = wid * 32 + j * 16 + lq * 4;
            float4 b4 = *(const float4*)&Bp2[col];
            f32x4 a = acc[i][j];
            float4 v;
            v.x = a[0] + b4.x; v.y = a[1] + b4.y;
            v.z = a[2] + b4.z; v.w = a[3] + b4.w;
            long row_off = (long)t * KNT * KH + (et == 0 ? (long)KN * KH : 0)
                         + (long)node * KH + col;
            if (l == 0) {
                v.x = fmaxf(v.x, 0.f); v.y = fmaxf(v.y, 0.f);
                v.z = fmaxf(v.z, 0.f); v.w = fmaxf(v.w, 0.f);
                unsigned short h0 = (unsigned short)bf16rn(v.x);
                unsigned short h1 = (unsigned short)bf16rn(v.y);
                unsigned short h2 = (unsigned short)bf16rn(v.z);
                unsigned short h3 = (unsigned short)bf16rn(v.w);
                *(uint2*)&x1o[row_off] = make_uint2(((unsigned)h1 << 16) | h0,
                                                    ((unsigned)h3 << 16) | h2);
            } else {
                *(float4*)&dout[row_off] = v;
            }
        }
    }
}

// ---------------------------------------------------------------------------
extern "C" void kernel_launch(void* const* d_in, const int* in_sizes, int n_in,
                              void* d_out_v, int out_size, void* d_ws, size_t ws_size,
                              hipStream_t stream) {
    const float* x_a    = (const float*)d_in[0];
    const float* x_d    = (const float*)d_in[1];
    const float* ea_ad  = (const float*)d_in[2];
    const float* ea_da  = (const float*)d_in[3];
    const int*   ei_ad  = (const int*)d_in[4];
    const int*   ei_da  = (const int*)d_in[5];
    const float* w1_ad  = (const float*)d_in[6];
    const float* b1_ad  = (const float*)d_in[7];
    const float* w2_ad  = (const float*)d_in[8];
    const float* b2_ad  = (const float*)d_in[9];
    const float* eps_ad = (const float*)d_in[10];
    const float* w1_da  = (const float*)d_in[11];
    const float* b1_da  = (const float*)d_in[12];
    const float* w2_da  = (const float*)d_in[13];
    const float* b2_da  = (const float*)d_in[14];
    const float* eps_da = (const float*)d_in[15];
    float* out = (float*)d_out_v;

    // workspace layout: x1 bf16 ping | offs | cur | pes | wsp  (~47 MB)
    unsigned short* x1 = (unsigned short*)d_ws;          // KT*KNT*KH bf16
    int*   offs = (int*)(x1 + (size_t)KT * KNT * KH);
    int*   cur  = offs + (size_t)8 * (KN + 1);
    int2*  pes  = (int2*)(cur + (size_t)8 * KN);
    short* wsp  = (short*)(pes + (size_t)8 * KE);        // 1,048,576 shorts

    hipMemsetAsync(cur, 0, (size_t)8 * KN * sizeof(int), stream);
    wsplit_k<<<256, 256, 0, stream>>>(w1_ad, w1_da, w2_ad, w2_da, wsp);

    dim3 eg((KE + 255) / 256, 8);
    count_k<<<eg, 256, 0, stream>>>(ei_ad, ei_da, cur);
    scan_k<<<8, 256, 0, stream>>>(cur, offs);
    fill_k<<<eg, 256, 0, stream>>>(ei_ad, ei_da, cur, pes);

    dim3 gg((KN + 31) / 32, 8);          // 625 x 8 = 5000 blocks
    // l=0: fp32 inputs -> bf16 x1 ;  l=1: bf16 x1 -> fp32 d_out
    fused_k<<<gg, 256, 0, stream>>>(x_a, x_d, (const unsigned short*)x1,
                                    ea_ad, ea_da, eps_ad, eps_da,
                                    offs, pes, wsp,
                                    b1_ad, b1_da, b2_ad, b2_da,
                                    x1, out, 0);
    fused_k<<<gg, 256, 0, stream>>>(x_a, x_d, (const unsigned short*)x1,
                                    ea_ad, ea_da, eps_ad, eps_da,
                                    offs, pes, wsp,
                                    b1_ad, b1_da, b2_ad, b2_da,
                                    x1, out, 1);
}

// Round 23
// 464.341 us; speedup vs baseline: 1.1183x; 1.0323x over previous
//
#include <hip/hip_runtime.h>

#define KT 4
#define KN 20000        // NA == ND == 20000
#define KE 100000
#define KH 128
#define KL 2
#define KNT 40000       // NA + ND

typedef __attribute__((ext_vector_type(8))) short short8v;
typedef __attribute__((ext_vector_type(4))) float f32x4;

__device__ __forceinline__ short bf16rn(float x) {
    unsigned u = __float_as_uint(x);
    u = (u + 0x7fffu + ((u >> 16) & 1u)) >> 16;
    return (short)u;
}
__device__ __forceinline__ float bf16tof(short h) {
    return __uint_as_float(((unsigned)(unsigned short)h) << 16);
}
__device__ __forceinline__ short8v mk8(uint2 a, uint2 b) {
    union { unsigned u[4]; short8v s; } c;
    c.u[0] = a.x; c.u[1] = a.y; c.u[2] = b.x; c.u[3] = b.y;
    return c.s;
}
__device__ __forceinline__ float4 unp4(uint2 g) {
    float4 r;
    r.x = __uint_as_float(g.x << 16);
    r.y = __uint_as_float(g.x & 0xffff0000u);
    r.z = __uint_as_float(g.y << 16);
    r.w = __uint_as_float(g.y & 0xffff0000u);
    return r;
}

// ---------------------------------------------------------------------------
// CSR build: counts -> scan -> fill (packed (edge, src) pairs).  All 8 z.
// ---------------------------------------------------------------------------
__global__ void count_k(const int* __restrict__ ei_ad, const int* __restrict__ ei_da,
                        int* __restrict__ cnt) {
    int e = blockIdx.x * 256 + threadIdx.x;
    int z = blockIdx.y;                 // z = t*2 + et
    if (e >= KE) return;
    int t = z >> 1, et = z & 1;
    const int* ei = et ? ei_da : ei_ad;
    int dst = ei[(t * 2 + 1) * KE + e];
    atomicAdd(&cnt[z * KN + dst], 1);
}

__global__ void scan_k(int* __restrict__ cnt, int* __restrict__ offs) {
    __shared__ int s[256];
    int z = blockIdx.x, tid = threadIdx.x;
    const int CH = (KN + 255) / 256;    // 79
    int n0 = tid * CH;
    int lim = n0 < KN ? min(CH, KN - n0) : 0;
    long base = (long)z * KN + n0;
    int sum = 0;
    for (int i = 0; i < lim; ++i) sum += cnt[base + i];
    s[tid] = sum;
    __syncthreads();
    for (int off = 1; off < 256; off <<= 1) {
        int v = (tid >= off) ? s[tid - off] : 0;
        __syncthreads();
        s[tid] += v;
        __syncthreads();
    }
    int run = s[tid] - sum;             // exclusive prefix
    for (int i = 0; i < lim; ++i) {
        int c = cnt[base + i];
        offs[(long)z * (KN + 1) + n0 + i] = run;
        cnt[base + i] = run;            // becomes fill cursor
        run += c;
    }
    if (tid == 0) offs[(long)z * (KN + 1) + KN] = KE;
}

__global__ void fill_k(const int* __restrict__ ei_ad, const int* __restrict__ ei_da,
                       int* __restrict__ cur, int2* __restrict__ pes) {
    int e = blockIdx.x * 256 + threadIdx.x;
    int z = blockIdx.y;
    if (e >= KE) return;
    int t = z >> 1, et = z & 1;
    const int* ei = et ? ei_da : ei_ad;
    int src = ei[(t * 2 + 0) * KE + e];
    int dst = ei[(t * 2 + 1) * KE + e];
    int pos = atomicAdd(&cur[z * KN + dst], 1);
    pes[(long)z * KE + pos] = make_int2(e, src);
}

// ---------------------------------------------------------------------------
// W pre-split: wsp[((mat*2+h)*4 + kc)*4096 + col*32 + kk], k = kc*32+kk.
// mat = arr*8 + (t*2+l), arr: 0=w1_ad 1=w1_da 2=w2_ad 3=w2_da.
// ---------------------------------------------------------------------------
__global__ __launch_bounds__(256)
void wsplit_k(const float* __restrict__ w1_ad, const float* __restrict__ w1_da,
              const float* __restrict__ w2_ad, const float* __restrict__ w2_da,
              short* __restrict__ wsp) {
    int mat = blockIdx.x >> 3, part = blockIdx.x & 7;   // mat 0..31
    int arr = mat >> 3, rem = mat & 7;   // rem = t*2+l
    const float* src = (arr == 0 ? w1_ad : arr == 1 ? w1_da : arr == 2 ? w2_ad : w2_da)
                       + (long)rem * KH * KH;
    #pragma unroll
    for (int p = 0; p < 8; ++p) {
        int idx = part * 2048 + p * 256 + threadIdx.x;  // 16384 elems total
        int k = idx >> 7, c = idx & 127;
        float v = src[idx];
        short hi = bf16rn(v);
        short lo = bf16rn(v - bf16tof(hi));
        int chunk = k >> 5, kk = k & 31;
        long ohi = ((long)(mat * 2 + 0) * 4 + chunk) * 4096 + c * 32 + kk;
        long olo = ((long)(mat * 2 + 1) * 4 + chunk) * 4096 + c * 32 + kk;
        wsp[ohi] = hi;
        wsp[olo] = lo;
    }
}

// ---------------------------------------------------------------------------
// Fully fused per-layer kernel, 32-NODE TILES (5000 blocks), 4-deep gather
// batches (R20 best configuration: 464.8 us, occupancy 54%).
//   phase 0: gather 32 nodes -> bf16 T in LDS (4 passes)
//   phase 1: mid = relu(T @ W1 + b1) -> T in-place
//   phase 2: out = [relu](T @ W2 + b2) -> lay_out
// 4 waves: each owns 32 rows x 32 cols (acc[2][2]).
// ALIASING + DTYPE: l=0 fp32 inputs -> bf16 x1 ; l=1 bf16 x1 -> fp32 d_out.
// ---------------------------------------------------------------------------
__global__ __launch_bounds__(256)
void fused_k(const float* __restrict__ xa, const float* __restrict__ xd,
             const unsigned short* __restrict__ x1b,
             const float* __restrict__ ea_ad, const float* __restrict__ ea_da,
             const float* __restrict__ eps_ad, const float* __restrict__ eps_da,
             const int* __restrict__ offs, const int2* __restrict__ pes,
             const short* __restrict__ wsp,
             const float* __restrict__ b1_ad, const float* __restrict__ b1_da,
             const float* __restrict__ b2_ad, const float* __restrict__ b2_da,
             unsigned short* __restrict__ x1o, float* __restrict__ dout,
             int l) {
    __shared__ short T[32][132];        // 8.4 KB, agg then mid (in-place)

    int z = blockIdx.y, t = z >> 1, et = z & 1;
    int tid = threadIdx.x;
    int r0 = blockIdx.x * 32;

    // ---- phase 0: gather this block's 32 nodes into T ----
    {
        const float* ea  = (et ? ea_da : ea_ad) + (long)t * KE * KH;
        const float* eps = et ? eps_da : eps_ad;
        float scale = 1.0f + eps[t * KL + l];
        const int2* pz = pes + (long)z * KE;
        int li = tid & 31, grp = tid >> 5;

        if (l == 0) {
            const float* src = et ? (xd + (long)t * KN * KH) : (xa + (long)t * KN * KH);
            const float* dst = et ? (xa + (long)t * KN * KH) : (xd + (long)t * KN * KH);
            #pragma unroll
            for (int p = 0; p < 4; ++p) {
                int lr = p * 8 + grp;
                int node = r0 + lr;
                float4 r = make_float4(0.f, 0.f, 0.f, 0.f);
                if (node < KN) {
                    float4 dv = *(const float4*)(dst + (long)node * KH + li * 4);
                    float4 acc = make_float4(0.f, 0.f, 0.f, 0.f);
                    int beg = offs[(long)z * (KN + 1) + node];
                    int end = offs[(long)z * (KN + 1) + node + 1];
                    if (beg < end) {
                        int last = end - 1;
                        for (int i = beg; i < end; i += 4) {
                            int i0 = min(i, last), i1 = min(i + 1, last),
                                i2 = min(i + 2, last), i3 = min(i + 3, last);
                            int2 p0 = pz[i0], p1 = pz[i1], p2 = pz[i2], p3 = pz[i3];
                            float4 e0 = *(const float4*)(ea + (long)p0.x * KH + li * 4);
                            float4 e1 = *(const float4*)(ea + (long)p1.x * KH + li * 4);
                            float4 e2 = *(const float4*)(ea + (long)p2.x * KH + li * 4);
                            float4 e3 = *(const float4*)(ea + (long)p3.x * KH + li * 4);
                            float4 x0 = *(const float4*)(src + (long)p0.y * KH + li * 4);
                            float4 x1v = *(const float4*)(src + (long)p1.y * KH + li * 4);
                            float4 x2 = *(const float4*)(src + (long)p2.y * KH + li * 4);
                            float4 x3 = *(const float4*)(src + (long)p3.y * KH + li * 4);
                            float4 es4[4] = {e0, e1, e2, e3};
                            float4 xs[4] = {x0, x1v, x2, x3};
                            #pragma unroll
                            for (int u = 0; u < 4; ++u) {
                                float m = (i + u <= last) ? 1.0f : 0.0f;
                                acc.x = fmaf(m, fmaxf(xs[u].x + es4[u].x, 0.f), acc.x);
                                acc.y = fmaf(m, fmaxf(xs[u].y + es4[u].y, 0.f), acc.y);
                                acc.z = fmaf(m, fmaxf(xs[u].z + es4[u].z, 0.f), acc.z);
                                acc.w = fmaf(m, fmaxf(xs[u].w + es4[u].w, 0.f), acc.w);
                            }
                        }
                    }
                    r.x = fmaf(scale, dv.x, acc.x);
                    r.y = fmaf(scale, dv.y, acc.y);
                    r.z = fmaf(scale, dv.z, acc.z);
                    r.w = fmaf(scale, dv.w, acc.w);
                }
                unsigned short h0 = (unsigned short)bf16rn(r.x);
                unsigned short h1 = (unsigned short)bf16rn(r.y);
                unsigned short h2 = (unsigned short)bf16rn(r.z);
                unsigned short h3 = (unsigned short)bf16rn(r.w);
                *(uint2*)&T[lr][li * 4] = make_uint2(((unsigned)h1 << 16) | h0,
                                                     ((unsigned)h3 << 16) | h2);
            }
        } else {
            const unsigned short* base = x1b + (long)t * KNT * KH;
            const unsigned short* srcb = et ? (base + (long)KN * KH) : base;
            const unsigned short* dstb = et ? base : (base + (long)KN * KH);
            #pragma unroll
            for (int p = 0; p < 4; ++p) {
                int lr = p * 8 + grp;
                int node = r0 + lr;
                float4 r = make_float4(0.f, 0.f, 0.f, 0.f);
                if (node < KN) {
                    float4 dv = unp4(*(const uint2*)(dstb + (long)node * KH + li * 4));
                    float4 acc = make_float4(0.f, 0.f, 0.f, 0.f);
                    int beg = offs[(long)z * (KN + 1) + node];
                    int end = offs[(long)z * (KN + 1) + node + 1];
                    if (beg < end) {
                        int last = end - 1;
                        for (int i = beg; i < end; i += 4) {
                            int i0 = min(i, last), i1 = min(i + 1, last),
                                i2 = min(i + 2, last), i3 = min(i + 3, last);
                            int2 p0 = pz[i0], p1 = pz[i1], p2 = pz[i2], p3 = pz[i3];
                            float4 e0 = *(const float4*)(ea + (long)p0.x * KH + li * 4);
                            float4 e1 = *(const float4*)(ea + (long)p1.x * KH + li * 4);
                            float4 e2 = *(const float4*)(ea + (long)p2.x * KH + li * 4);
                            float4 e3 = *(const float4*)(ea + (long)p3.x * KH + li * 4);
                            uint2 g0 = *(const uint2*)(srcb + (long)p0.y * KH + li * 4);
                            uint2 g1 = *(const uint2*)(srcb + (long)p1.y * KH + li * 4);
                            uint2 g2 = *(const uint2*)(srcb + (long)p2.y * KH + li * 4);
                            uint2 g3 = *(const uint2*)(srcb + (long)p3.y * KH + li * 4);
                            float4 es4[4] = {e0, e1, e2, e3};
                            float4 xs[4] = {unp4(g0), unp4(g1), unp4(g2), unp4(g3)};
                            #pragma unroll
                            for (int u = 0; u < 4; ++u) {
                                float m = (i + u <= last) ? 1.0f : 0.0f;
                                acc.x = fmaf(m, fmaxf(xs[u].x + es4[u].x, 0.f), acc.x);
                                acc.y = fmaf(m, fmaxf(xs[u].y + es4[u].y, 0.f), acc.y);
                                acc.z = fmaf(m, fmaxf(xs[u].z + es4[u].z, 0.f), acc.z);
                                acc.w = fmaf(m, fmaxf(xs[u].w + es4[u].w, 0.f), acc.w);
                            }
                        }
                    }
                    r.x = fmaf(scale, dv.x, acc.x);
                    r.y = fmaf(scale, dv.y, acc.y);
                    r.z = fmaf(scale, dv.z, acc.z);
                    r.w = fmaf(scale, dv.w, acc.w);
                }
                unsigned short h0 = (unsigned short)bf16rn(r.x);
                unsigned short h1 = (unsigned short)bf16rn(r.y);
                unsigned short h2 = (unsigned short)bf16rn(r.z);
                unsigned short h3 = (unsigned short)bf16rn(r.w);
                *(uint2*)&T[lr][li * 4] = make_uint2(((unsigned)h1 << 16) | h0,
                                                     ((unsigned)h3 << 16) | h2);
            }
        }
    }
    __syncthreads();

    int mat1 = (0 * 2 + et) * 8 + t * 2 + l;
    int mat2 = (1 * 2 + et) * 8 + t * 2 + l;
    const float* Bp1 = (et ? b1_da : b1_ad) + (long)(t * KL + l) * KH;
    const float* Bp2 = (et ? b2_da : b2_ad) + (long)(t * KL + l) * KH;

    int lane = tid & 63, wid = tid >> 6;     // wave owns 32 rows x 32 cols
    int lrow = lane & 15, lq = lane >> 4;

    f32x4 acc[2][2];
    #pragma unroll
    for (int i = 0; i < 2; ++i)
        #pragma unroll
        for (int j = 0; j < 2; ++j) acc[i][j] = (f32x4){0.f, 0.f, 0.f, 0.f};

    // ---- phase 1: acc = T(agg) @ W1 ----
    #pragma unroll
    for (int kc = 0; kc < 4; ++kc) {
        const short* whp = wsp + ((long)(mat1 * 2 + 0) * 4 + kc) * 4096;
        const short* wlp = wsp + ((long)(mat1 * 2 + 1) * 4 + kc) * 4096;
        short8v bhi[2], blo[2];
        #pragma unroll
        for (int j = 0; j < 2; ++j) {
            int off = (wid * 32 + j * 16 + lrow) * 32 + lq * 8;
            bhi[j] = *(const short8v*)(whp + off);
            blo[j] = *(const short8v*)(wlp + off);
        }
        #pragma unroll
        for (int i = 0; i < 2; ++i) {
            int lr = i * 16 + lrow;
            int co = kc * 32 + lq * 8;
            short8v ahi = mk8(*(const uint2*)&T[lr][co],
                              *(const uint2*)&T[lr][co + 4]);
            #pragma unroll
            for (int j = 0; j < 2; ++j) {
                acc[i][j] = __builtin_amdgcn_mfma_f32_16x16x32_bf16(bhi[j], ahi, acc[i][j], 0, 0, 0);
                acc[i][j] = __builtin_amdgcn_mfma_f32_16x16x32_bf16(blo[j], ahi, acc[i][j], 0, 0, 0);
            }
        }
    }

    __syncthreads();   // phase-1 reads complete before in-place overwrite

    // ---- epilogue 1: bias + relu -> bf16 -> T (in place) ----
    #pragma unroll
    for (int i = 0; i < 2; ++i) {
        int lr = i * 16 + lrow;
        #pragma unroll
        for (int j = 0; j < 2; ++j) {
            int col = wid * 32 + j * 16 + lq * 4;
            float4 b4 = *(const float4*)&Bp1[col];
            f32x4 a = acc[i][j];
            float v0 = fmaxf(a[0] + b4.x, 0.f);
            float v1 = fmaxf(a[1] + b4.y, 0.f);
            float v2 = fmaxf(a[2] + b4.z, 0.f);
            float v3 = fmaxf(a[3] + b4.w, 0.f);
            unsigned short h0 = (unsigned short)bf16rn(v0);
            unsigned short h1 = (unsigned short)bf16rn(v1);
            unsigned short h2 = (unsigned short)bf16rn(v2);
            unsigned short h3 = (unsigned short)bf16rn(v3);
            *(uint2*)&T[lr][col] = make_uint2(((unsigned)h1 << 16) | h0,
                                              ((unsigned)h3 << 16) | h2);
        }
    }
    __syncthreads();

    // ---- phase 2: acc = T(mid) @ W2 ----
    #pragma unroll
    for (int i = 0; i < 2; ++i)
        #pragma unroll
        for (int j = 0; j < 2; ++j) acc[i][j] = (f32x4){0.f, 0.f, 0.f, 0.f};

    #pragma unroll
    for (int kc = 0; kc < 4; ++kc) {
        const short* whp = wsp + ((long)(mat2 * 2 + 0) * 4 + kc) * 4096;
        const short* wlp = wsp + ((long)(mat2 * 2 + 1) * 4 + kc) * 4096;
        short8v bhi[2], blo[2];
        #pragma unroll
        for (int j = 0; j < 2; ++j) {
            int off = (wid * 32 + j * 16 + lrow) * 32 + lq * 8;
            bhi[j] = *(const short8v*)(whp + off);
            blo[j] = *(const short8v*)(wlp + off);
        }
        #pragma unroll
        for (int i = 0; i < 2; ++i) {
            int lr = i * 16 + lrow;
            int co = kc * 32 + lq * 8;
            short8v ahi = mk8(*(const uint2*)&T[lr][co],
                              *(const uint2*)&T[lr][co + 4]);
            #pragma unroll
            for (int j = 0; j < 2; ++j) {
                acc[i][j] = __builtin_amdgcn_mfma_f32_16x16x32_bf16(bhi[j], ahi, acc[i][j], 0, 0, 0);
                acc[i][j] = __builtin_amdgcn_mfma_f32_16x16x32_bf16(blo[j], ahi, acc[i][j], 0, 0, 0);
            }
        }
    }

    // ---- epilogue 2 ----
    #pragma unroll
    for (int i = 0; i < 2; ++i) {
        int node = r0 + i * 16 + lrow;
        if (node >= KN) continue;
        #pragma unroll
        for (int j = 0; j < 2; ++j) {
            int col = wid * 32 + j * 16 + lq * 4;
            float4 b4 = *(const float4*)&Bp2[col];
            f32x4 a = acc[i][j];
            float4 v;
            v.x = a[0] + b4.x; v.y = a[1] + b4.y;
            v.z = a[2] + b4.z; v.w = a[3] + b4.w;
            long row_off = (long)t * KNT * KH + (et == 0 ? (long)KN * KH : 0)
                         + (long)node * KH + col;
            if (l == 0) {
                v.x = fmaxf(v.x, 0.f); v.y = fmaxf(v.y, 0.f);
                v.z = fmaxf(v.z, 0.f); v.w = fmaxf(v.w, 0.f);
                unsigned short h0 = (unsigned short)bf16rn(v.x);
                unsigned short h1 = (unsigned short)bf16rn(v.y);
                unsigned short h2 = (unsigned short)bf16rn(v.z);
                unsigned short h3 = (unsigned short)bf16rn(v.w);
                *(uint2*)&x1o[row_off] = make_uint2(((unsigned)h1 << 16) | h0,
                                                    ((unsigned)h3 << 16) | h2);
            } else {
                *(float4*)&dout[row_off] = v;
            }
        }
    }
}

// ---------------------------------------------------------------------------
extern "C" void kernel_launch(void* const* d_in, const int* in_sizes, int n_in,
                              void* d_out_v, int out_size, void* d_ws, size_t ws_size,
                              hipStream_t stream) {
    const float* x_a    = (const float*)d_in[0];
    const float* x_d    = (const float*)d_in[1];
    const float* ea_ad  = (const float*)d_in[2];
    const float* ea_da  = (const float*)d_in[3];
    const int*   ei_ad  = (const int*)d_in[4];
    const int*   ei_da  = (const int*)d_in[5];
    const float* w1_ad  = (const float*)d_in[6];
    const float* b1_ad  = (const float*)d_in[7];
    const float* w2_ad  = (const float*)d_in[8];
    const float* b2_ad  = (const float*)d_in[9];
    const float* eps_ad = (const float*)d_in[10];
    const float* w1_da  = (const float*)d_in[11];
    const float* b1_da  = (const float*)d_in[12];
    const float* w2_da  = (const float*)d_in[13];
    const float* b2_da  = (const float*)d_in[14];
    const float* eps_da = (const float*)d_in[15];
    float* out = (float*)d_out_v;

    // workspace layout: x1 bf16 ping | offs | cur | pes | wsp  (~47 MB)
    unsigned short* x1 = (unsigned short*)d_ws;          // KT*KNT*KH bf16
    int*   offs = (int*)(x1 + (size_t)KT * KNT * KH);
    int*   cur  = offs + (size_t)8 * (KN + 1);
    int2*  pes  = (int2*)(cur + (size_t)8 * KN);
    short* wsp  = (short*)(pes + (size_t)8 * KE);        // 1,048,576 shorts

    hipMemsetAsync(cur, 0, (size_t)8 * KN * sizeof(int), stream);
    wsplit_k<<<256, 256, 0, stream>>>(w1_ad, w1_da, w2_ad, w2_da, wsp);

    dim3 eg((KE + 255) / 256, 8);
    count_k<<<eg, 256, 0, stream>>>(ei_ad, ei_da, cur);
    scan_k<<<8, 256, 0, stream>>>(cur, offs);
    fill_k<<<eg, 256, 0, stream>>>(ei_ad, ei_da, cur, pes);

    dim3 gg((KN + 31) / 32, 8);          // 625 x 8 = 5000 blocks
    // l=0: fp32 inputs -> bf16 x1 ;  l=1: bf16 x1 -> fp32 d_out
    fused_k<<<gg, 256, 0, stream>>>(x_a, x_d, (const unsigned short*)x1,
                                    ea_ad, ea_da, eps_ad, eps_da,
                                    offs, pes, wsp,
                                    b1_ad, b1_da, b2_ad, b2_da,
                                    x1, out, 0);
    fused_k<<<gg, 256, 0, stream>>>(x_a, x_d, (const unsigned short*)x1,
                                    ea_ad, ea_da, eps_ad, eps_da,
                                    offs, pes, wsp,
                                    b1_ad, b1_da, b2_ad, b2_da,
                                    x1, out, 1);
}